// Round 13
// baseline (341.516 us; speedup 1.0000x reference)
//
#include <hip/hip_runtime.h>
#include <hip/hip_bf16.h>
#include <math.h>

constexpr int SEQ    = 2048;
constexpr int NH     = 16;
constexpr int HEAVY  = 204;   // int(0.1*2048)
constexpr int RECENT = 204;   // int(0.1*2048)
constexpr int SPLIT  = 4;     // flash stats/colsum split factor
constexpr float SCALE = 0.08838834764831845f; // 128^-0.5
constexpr int ONSZ   = NH * SEQ * 128;        // floats per O-partial slice

typedef _Float16 half8 __attribute__((ext_vector_type(8)));
typedef float f32x4 __attribute__((ext_vector_type(4)));

typedef __attribute__((address_space(1))) const void cg_void;
typedef __attribute__((address_space(3))) void l_void;

// ---------- prep: z=0..2 -> transpose Wq/Wk/Wv into WT f16 [N][K]; z=3 -> hs f32->f16 ----------
__global__ __launch_bounds__(256) void prep(
    const float* __restrict__ hs, _Float16* __restrict__ hsH,
    const float* __restrict__ Wq, const float* __restrict__ Wk,
    const float* __restrict__ Wv, _Float16* __restrict__ WT) {
  int z = blockIdx.z;
  if (z < 3) {
    const float* W = (z == 0) ? Wq : ((z == 1) ? Wk : Wv);
    int N = (z == 0) ? 2048 : 512;
    size_t dstoff = (z == 0) ? 0 : ((z == 1) ? (size_t)2048 * 2048 : (size_t)2560 * 2048);
    int n0 = blockIdx.x * 64, k0 = blockIdx.y * 64;
    if (n0 >= N) return;
    __shared__ float T[64][65];
    int c = threadIdx.x & 63, rq = threadIdx.x >> 6;
#pragma unroll
    for (int u = 0; u < 16; ++u) {
      int r = rq * 16 + u;
      T[r][c] = W[(size_t)(k0 + r) * N + n0 + c];
    }
    __syncthreads();
#pragma unroll
    for (int u = 0; u < 16; ++u) {
      int r = rq * 16 + u;
      WT[dstoff + (size_t)(n0 + r) * 2048 + k0 + c] = (_Float16)T[c][r];
    }
  } else {
    int fb = blockIdx.y * 32 + blockIdx.x;
    int i = (fb * 256 + threadIdx.x) * 16;
#pragma unroll
    for (int u = 0; u < 4; ++u) {
      float4 v = *(const float4*)(hs + i + u * 4);
      hsH[i + u * 4 + 0] = (_Float16)v.x;
      hsH[i + u * 4 + 1] = (_Float16)v.y;
      hsH[i + u * 4 + 2] = (_Float16)v.z;
      hsH[i + u * 4 + 3] = (_Float16)v.w;
    }
  }
}

// ---------- transpose + convert: W f32 [K][N] -> WT f16 [N][K] (Wo) ----------
__global__ __launch_bounds__(256) void transpose_h(
    const float* __restrict__ W, _Float16* __restrict__ WT, int K, int N) {
  __shared__ float T[64][65];
  int c = threadIdx.x & 63, rq = threadIdx.x >> 6;
  int n0 = blockIdx.x * 64, k0 = blockIdx.y * 64;
#pragma unroll
  for (int u = 0; u < 16; ++u) {
    int r = rq * 16 + u;
    T[r][c] = W[(size_t)(k0 + r) * N + n0 + c];
  }
  __syncthreads();
#pragma unroll
  for (int u = 0; u < 16; ++u) {
    int r = rq * 16 + u;
    WT[(size_t)(n0 + r) * K + k0 + c] = (_Float16)T[c][r];
  }
}

// ---------- MFMA f16 GEMM, BK=64, XOR-swizzled LDS, XCD block swizzle, split-K ----------
__global__ __launch_bounds__(256) void gemm_h(
    const _Float16* __restrict__ A, const _Float16* __restrict__ BT,
    const float* __restrict__ bq, const float* __restrict__ bk,
    const float* __restrict__ bv, float* __restrict__ C0, float* __restrict__ C1,
    int M, int N, int K)
{
  __shared__ _Float16 As[128 * 64];
  __shared__ _Float16 Bs[128 * 64];
  int tid = threadIdx.x, lane = tid & 63, wave = tid >> 6;
  int wm = (wave & 1) * 64, wn = (wave >> 1) * 64;
  int mq = lane & 15, quad = lane >> 4;
  int kz = blockIdx.z, nz = gridDim.z;
  int kchunk = K / nz;
  int kbeg = kz * kchunk, kend = kbeg + kchunk;
  float* C = kz ? C1 : C0;

  int gx = gridDim.x;
  int nwg = gx * gridDim.y;
  int bid = blockIdx.y * gx + blockIdx.x;
  if ((nwg & 7) == 0) {
    int cpx = nwg >> 3;
    bid = (bid & 7) * cpx + (bid >> 3);
  }
  int m0 = (bid / gx) * 128, n0 = (bid % gx) * 128;

  f32x4 acc[4][4] = {};

  int rstage = wave * 32 + (lane >> 3);
  int qs = ((lane & 7) ^ (lane >> 3)) * 8;         // pre-swizzled k-slot (halfs)
  const _Float16* gA = A  + (size_t)(m0 + rstage) * K + qs;
  const _Float16* gB = BT + (size_t)(n0 + rstage) * K + qs;
  _Float16* lA = &As[(wave * 32) * 64];
  _Float16* lB = &Bs[(wave * 32) * 64];

  int rsw = mq & 7;                                // read-side row swizzle key

  for (int k0 = kbeg; k0 < kend; k0 += 64) {
#pragma unroll
    for (int c = 0; c < 4; ++c) {
      __builtin_amdgcn_global_load_lds((cg_void*)(gA + (size_t)(8 * c) * K + k0),
                                       (l_void*)(lA + (8 * c) * 64), 16, 0, 0);
      __builtin_amdgcn_global_load_lds((cg_void*)(gB + (size_t)(8 * c) * K + k0),
                                       (l_void*)(lB + (8 * c) * 64), 16, 0, 0);
    }
    __syncthreads();
#pragma unroll
    for (int ks2 = 0; ks2 < 2; ++ks2) {
      int sw = ((ks2 * 4 + quad) ^ rsw) * 8;
      half8 af[4], bf[4];
#pragma unroll
      for (int t4 = 0; t4 < 4; ++t4) {
        af[t4] = *(const half8*)&As[(wm + t4 * 16 + mq) * 64 + sw];
        bf[t4] = *(const half8*)&Bs[(wn + t4 * 16 + mq) * 64 + sw];
      }
#pragma unroll
      for (int mt = 0; mt < 4; ++mt)
#pragma unroll
        for (int nt = 0; nt < 4; ++nt)
          acc[mt][nt] = __builtin_amdgcn_mfma_f32_16x16x32_f16(af[mt], bf[nt], acc[mt][nt], 0, 0, 0);
    }
    __syncthreads();
  }

#pragma unroll
  for (int mt = 0; mt < 4; ++mt)
#pragma unroll
    for (int nt = 0; nt < 4; ++nt) {
      int n = n0 + wn + nt * 16 + mq;
      float bb = 0.f;
      if (bq && kz == 0)
        bb = (n < 2048) ? bq[n] : ((n < 2560) ? bk[n - 2048] : bv[n - 2560]);
#pragma unroll
      for (int r = 0; r < 4; ++r) {
        int m = m0 + wm + mt * 16 + quad * 4 + r;
        C[(size_t)m * N + n] = acc[mt][nt][r] + bb;
      }
    }
}

// ---------- add partial into out ----------
__global__ void addout(float* __restrict__ out, const float* __restrict__ p1, int n) {
  int i = (blockIdx.x * 256 + threadIdx.x) * 4;
  if (i + 3 < n) {
    float4 a = *(const float4*)(out + i);
    float4 b = *(const float4*)(p1 + i);
    a.x += b.x; a.y += b.y; a.z += b.z; a.w += b.w;
    *(float4*)(out + i) = a;
  } else {
    for (int u = i; u < n; ++u) out[u] += p1[u];
  }
}

// ---------- postproc: qkv partials -> RoPE'd qh (PRE-SCALED by SCALE) / kh + vh ----------
__global__ void postproc(const float* __restrict__ qkv, const float* __restrict__ qkv1,
                         const float* __restrict__ cosb, const float* __restrict__ sinb,
                         _Float16* __restrict__ qh, _Float16* __restrict__ kh,
                         _Float16* __restrict__ vh) {
  int idx = blockIdx.x * 256 + threadIdx.x;
  const int NQ = SEQ * 16 * 64, NK = SEQ * 4 * 64, NV = SEQ * 4 * 128;
  bool sp = (qkv1 != nullptr);
  if (idx < NQ) {
    int d = idx & 63; int rest = idx >> 6; int h = rest & 15; int s = rest >> 4;
    size_t o = (size_t)s * 3072 + h * 128;
    float x1 = qkv[o + d]      + (sp ? qkv1[o + d] : 0.f);
    float x2 = qkv[o + d + 64] + (sp ? qkv1[o + d + 64] : 0.f);
    float c1 = cosb[(size_t)s * 128 + d], c2 = cosb[(size_t)s * 128 + d + 64];
    float s1 = sinb[(size_t)s * 128 + d], s2 = sinb[(size_t)s * 128 + d + 64];
    qh[(size_t)s * 2048 + h * 128 + d]      = (_Float16)((x1 * c1 - x2 * s1) * SCALE);
    qh[(size_t)s * 2048 + h * 128 + d + 64] = (_Float16)((x2 * c2 + x1 * s2) * SCALE);
  } else if (idx < NQ + NK) {
    int r = idx - NQ;
    int d = r & 63; int rest = r >> 6; int h = rest & 3; int s = rest >> 2;
    size_t o = (size_t)s * 3072 + 2048 + h * 128;
    float x1 = qkv[o + d]      + (sp ? qkv1[o + d] : 0.f);
    float x2 = qkv[o + d + 64] + (sp ? qkv1[o + d + 64] : 0.f);
    float c1 = cosb[(size_t)s * 128 + d], c2 = cosb[(size_t)s * 128 + d + 64];
    float s1 = sinb[(size_t)s * 128 + d], s2 = sinb[(size_t)s * 128 + d + 64];
    kh[(size_t)s * 512 + h * 128 + d]      = (_Float16)(x1 * c1 - x2 * s1);
    kh[(size_t)s * 512 + h * 128 + d + 64] = (_Float16)(x2 * c2 + x1 * s2);
  } else if (idx < NQ + NK + NV) {
    int r = idx - NQ - NK;
    int d = r & 127; int rest = r >> 7; int h = rest & 3; int s = rest >> 2;
    size_t o = (size_t)s * 3072 + 2560 + h * 128 + d;
    float x = qkv[o] + (sp ? qkv1[o] : 0.f);
    vh[(size_t)s * 512 + h * 128 + d] = (_Float16)x;
  }
}

// ---------- S1: denominator L_i = sum_{j<=i} exp(s_ij), reference point 0 ----------
__global__ __launch_bounds__(256) void flashstats(
    const _Float16* __restrict__ qh, const _Float16* __restrict__ kh,
    float* __restrict__ rowlP)
{
  int sp = blockIdx.x;                    // j-split 0..SPLIT-1
  int ib = blockIdx.y;
  int i0 = ib * 128, h = blockIdx.z, kvh = h >> 2;
  __shared__ _Float16 Ks[128][136];
  int tid = threadIdx.x, lane = tid & 63, wave = tid >> 6;
  int mq = lane & 15, quad = lane >> 4;
  int wm = wave * 32;

  half8 aq[2][4];
#pragma unroll
  for (int rt = 0; rt < 2; ++rt)
#pragma unroll
    for (int ks = 0; ks < 4; ++ks)
      aq[rt][ks] = *(const half8*)(qh + (size_t)(i0 + wm + rt * 16 + mq) * 2048 + h * 128 + ks * 32 + quad * 8);

  float runl[2][4] = {};

  int nblk = ib + 1;
  int jb_lo = (sp * nblk) / SPLIT;
  int jb_hi = ((sp + 1) * nblk) / SPLIT;
  for (int jb = jb_lo; jb < jb_hi; ++jb) {
    int j0 = jb * 128;
    __syncthreads();
#pragma unroll
    for (int u = 0; u < 8; ++u) {
      int unit = u * 256 + tid;
      int r = unit >> 4, c8 = (unit & 15) * 8;
      *(half8*)&Ks[r][c8] = *(const half8*)(kh + (size_t)(j0 + r) * 512 + kvh * 128 + c8);
    }
    __syncthreads();

    f32x4 acc[2][8] = {};
#pragma unroll
    for (int ks = 0; ks < 4; ++ks) {
      half8 bf[8];
#pragma unroll
      for (int ct = 0; ct < 8; ++ct) bf[ct] = *(const half8*)&Ks[ct * 16 + mq][ks * 32 + quad * 8];
#pragma unroll
      for (int rt = 0; rt < 2; ++rt)
#pragma unroll
        for (int ct = 0; ct < 8; ++ct)
          acc[rt][ct] = __builtin_amdgcn_mfma_f32_16x16x32_f16(aq[rt][ks], bf[ct], acc[rt][ct], 0, 0, 0);
    }

    if (jb < ib) {
#pragma unroll
      for (int rt = 0; rt < 2; ++rt)
#pragma unroll
        for (int r = 0; r < 4; ++r) {
          float ps = 0.f;
#pragma unroll
          for (int ct = 0; ct < 8; ++ct) ps += __expf(acc[rt][ct][r]);
          runl[rt][r] += ps;
        }
    } else {
#pragma unroll
      for (int rt = 0; rt < 2; ++rt) {
        int rbase = i0 + wm + rt * 16 + quad * 4;
#pragma unroll
        for (int r = 0; r < 4; ++r) {
          float ps = 0.f;
#pragma unroll
          for (int ct = 0; ct < 8; ++ct) {
            int j = j0 + ct * 16 + mq;
            ps += (j <= rbase + r) ? __expf(acc[rt][ct][r]) : 0.f;
          }
          runl[rt][r] += ps;
        }
      }
    }
  }

#pragma unroll
  for (int rt = 0; rt < 2; ++rt)
#pragma unroll
    for (int r = 0; r < 4; ++r) {
      float l = runl[rt][r];
      for (int off = 1; off < 16; off <<= 1) l += __shfl_xor(l, off, 64);
      runl[rt][r] = l;
    }

  if (mq == 0) {
#pragma unroll
    for (int rt = 0; rt < 2; ++rt)
#pragma unroll
      for (int r = 0; r < 4; ++r) {
        int i = i0 + wm + rt * 16 + quad * 4 + r;
        rowlP[sp * (NH * SEQ) + h * SEQ + i] = runl[rt][r];
      }
  }
}

// ---------- merge: rowli[i] = 1 / sum_s rowlP[s][i] ----------
__global__ void mergestats(const float* __restrict__ rowlP, float* __restrict__ rowli) {
  int i = blockIdx.x * 256 + threadIdx.x;
  if (i >= NH * SEQ) return;
  float l = 0.f;
#pragma unroll
  for (int s = 0; s < SPLIT; ++s) l += rowlP[s * (NH * SEQ) + i];
  rowli[i] = (l > 0.f) ? 1.f / l : 0.f;
}

// ---------- S2: colsum[h][j] = sum_i exp(s_ij) * rowli[i], Q streamed, i-split ----------
__global__ __launch_bounds__(256) void flashcolsum(
    const _Float16* __restrict__ qh, const _Float16* __restrict__ kh,
    const float* __restrict__ rowli, float* __restrict__ colsumP)
{
  int sp = blockIdx.x;                    // i-split 0..SPLIT-1
  int jb = blockIdx.y;
  int j0 = jb * 128, h = blockIdx.z, kvh = h >> 2;
  __shared__ _Float16 Ks[128][136];
  __shared__ float colred[4][128];
  int tid = threadIdx.x, lane = tid & 63, wave = tid >> 6;
  int mq = lane & 15, quad = lane >> 4;
  int wm = wave * 32;

#pragma unroll
  for (int u = 0; u < 8; ++u) {
    int unit = u * 256 + tid;
    int r = unit >> 4, c8 = (unit & 15) * 8;
    *(half8*)&Ks[r][c8] = *(const half8*)(kh + (size_t)(j0 + r) * 512 + kvh * 128 + c8);
  }
  __syncthreads();

  float colacc[8] = {};
  int n = SEQ / 128 - jb;
  int ib_lo = jb + (sp * n) / SPLIT;
  int ib_hi = jb + ((sp + 1) * n) / SPLIT;
  for (int ib = ib_lo; ib < ib_hi; ++ib) {
    int i0 = ib * 128;

    f32x4 acc[2][8] = {};
#pragma unroll
    for (int ks = 0; ks < 4; ++ks) {
      half8 af[2], bf[8];
#pragma unroll
      for (int rt = 0; rt < 2; ++rt)
        af[rt] = *(const half8*)(qh + (size_t)(i0 + wm + rt * 16 + mq) * 2048 + h * 128 + ks * 32 + quad * 8);
#pragma unroll
      for (int ct = 0; ct < 8; ++ct) bf[ct] = *(const half8*)&Ks[ct * 16 + mq][ks * 32 + quad * 8];
#pragma unroll
      for (int rt = 0; rt < 2; ++rt)
#pragma unroll
        for (int ct = 0; ct < 8; ++ct)
          acc[rt][ct] = __builtin_amdgcn_mfma_f32_16x16x32_f16(af[rt], bf[ct], acc[rt][ct], 0, 0, 0);
    }

    if (ib > jb) {
#pragma unroll
      for (int rt = 0; rt < 2; ++rt) {
        int rbase = i0 + wm + rt * 16 + quad * 4;
        float ri[4];
#pragma unroll
        for (int r = 0; r < 4; ++r) ri[r] = rowli[h * SEQ + rbase + r];
#pragma unroll
        for (int ct = 0; ct < 8; ++ct) {
          float cp = 0.f;
#pragma unroll
          for (int r = 0; r < 4; ++r) cp += __expf(acc[rt][ct][r]) * ri[r];
          colacc[ct] += cp;
        }
      }
    } else {
#pragma unroll
      for (int rt = 0; rt < 2; ++rt) {
        int rbase = i0 + wm + rt * 16 + quad * 4;
        float ri[4];
#pragma unroll
        for (int r = 0; r < 4; ++r) ri[r] = rowli[h * SEQ + rbase + r];
#pragma unroll
        for (int ct = 0; ct < 8; ++ct) {
          int j = j0 + ct * 16 + mq;
          float cp = 0.f;
#pragma unroll
          for (int r = 0; r < 4; ++r) {
            if (j <= rbase + r) cp += __expf(acc[rt][ct][r]) * ri[r];
          }
          colacc[ct] += cp;
        }
      }
    }
  }
#pragma unroll
  for (int ct = 0; ct < 8; ++ct) {
    float v = colacc[ct];
    v += __shfl_xor(v, 16, 64);
    v += __shfl_xor(v, 32, 64);
    colacc[ct] = v;
  }
  __syncthreads();
  if (quad == 0) {
#pragma unroll
    for (int ct = 0; ct < 8; ++ct) colred[wave][ct * 16 + mq] = colacc[ct];
  }
  __syncthreads();
  if (tid < 128)
    colsumP[sp * (NH * SEQ) + h * SEQ + j0 + tid] =
        colred[0][tid] + colred[1][tid] + colred[2][tid] + colred[3][tid];
}

// ---------- top-HEAVY per head via radix select, parallel suffix-scan bucket pick ----------
__global__ __launch_bounds__(256) void topk_radix(const float* __restrict__ colsumP,
                                                  int* __restrict__ hidx) {
  int h = blockIdx.x, t = threadIdx.x;
  __shared__ unsigned vals[SEQ];
  __shared__ int hist[256];
  __shared__ int scanbuf[256];
  __shared__ unsigned s_prefix;
  __shared__ int s_k;

  for (int j = t; j < SEQ; j += 256) {
    float cs = 0.f;
#pragma unroll
    for (int s = 0; s < SPLIT; ++s) cs += colsumP[s * (NH * SEQ) + h * SEQ + j];
    vals[j] = __float_as_uint(cs);
  }

  unsigned prefix = 0, maskFixed = 0;
  int k = HEAVY;
  for (int pass = 0; pass < 4; ++pass) {
    int shift = 24 - pass * 8;
    hist[t] = 0;
    __syncthreads();
    for (int j = t; j < SEQ; j += 256) {
      unsigned v = vals[j];
      if ((v & maskFixed) == prefix) atomicAdd(&hist[(v >> shift) & 255], 1);
    }
    __syncthreads();
    scanbuf[t] = hist[t];
    __syncthreads();
    for (int off = 1; off < 256; off <<= 1) {
      int x = (t + off < 256) ? scanbuf[t + off] : 0;
      __syncthreads();
      scanbuf[t] += x;
      __syncthreads();
    }
    int S = scanbuf[t];
    int Snext = (t < 255) ? scanbuf[t + 1] : 0;
    if (S >= k && Snext < k) {
      s_prefix = prefix | ((unsigned)t << shift);
      s_k = k - (S - hist[t]);
    }
    __syncthreads();
    prefix = s_prefix;
    k = s_k;
    maskFixed |= (0xFFu << shift);
    __syncthreads();
  }
  unsigned T = prefix;
  int tieNeed = k;

  int base = t * 8;
  int cG = 0, cT = 0;
#pragma unroll
  for (int u = 0; u < 8; ++u) {
    unsigned v = vals[base + u];
    if (v > T) cG++;
    else if (v == T) cT++;
  }
  scanbuf[t] = cG; __syncthreads();
  for (int off = 1; off < 256; off <<= 1) {
    int x = (t >= off) ? scanbuf[t - off] : 0;
    __syncthreads();
    scanbuf[t] += x;
    __syncthreads();
  }
  int exG = scanbuf[t] - cG;
  int totG = scanbuf[255];
  __syncthreads();
  scanbuf[t] = cT; __syncthreads();
  for (int off = 1; off < 256; off <<= 1) {
    int x = (t >= off) ? scanbuf[t - off] : 0;
    __syncthreads();
    scanbuf[t] += x;
    __syncthreads();
  }
  int exT = scanbuf[t] - cT;

  int slotG = exG;
  int slotT = totG + exT;
#pragma unroll
  for (int u = 0; u < 8; ++u) {
    unsigned v = vals[base + u];
    if (v > T) {
      hidx[h * HEAVY + slotG] = base + u;
      slotG++;
    } else if (v == T) {
      if (slotT < totG + tieNeed) hidx[h * HEAVY + slotT] = base + u;
      slotT++;
    }
  }
}

// ---------- attn3: band/heavy z-split, additive partials (reference-0 softmax) ----------
// z=0: band tiles; z=1: heavy tiles.  Each writes (Sum exp*V, Sum exp) partials in
// f32; combineO sums and normalizes.  2 barriers/tile (end barrier proven redundant:
// PV reads Vs/Ps only; next bar1 orders Vs reuse).  V prefetched one tile ahead.
__global__ __launch_bounds__(256) void attn3(
    const _Float16* __restrict__ qh, const _Float16* __restrict__ kh,
    const _Float16* __restrict__ vh, const int* __restrict__ hidx,
    float* __restrict__ On0, float* __restrict__ On1, float* __restrict__ lp)
{
  constexpr int TB = 64;
  int i0 = blockIdx.x * 64, h = blockIdx.y, kvh = h >> 2;
  int zz = blockIdx.z;
  __shared__ _Float16 Ks[64][136];        // K tile
  __shared__ _Float16 Vs[128][72];        // V^T tile
  __shared__ _Float16 Ps[64][72];         // P tile (wave-local rows)
  __shared__ int shx[HEAVY];
  int tid = threadIdx.x, lane = tid & 63, wave = tid >> 6;
  int mq = lane & 15, quad = lane >> 4;
  int wm = wave * 16;

  int tb_lo = max(0, i0 - RECENT) >> 6;
  int tb_hi = (i0 + 63) >> 6;
  int nband = tb_hi - tb_lo + 1;
  int nheavy = (i0 + 63 > RECENT) ? ((HEAVY + TB - 1) / TB) : 0;
  int ntiles = zz ? nheavy : nband;

  if (zz)
    for (int e = tid; e < HEAVY; e += 256) shx[e] = hidx[h * HEAVY + e];

  half8 aq[4];
#pragma unroll
  for (int ks = 0; ks < 4; ++ks)
    aq[ks] = *(const half8*)(qh + (size_t)(i0 + wm + mq) * 2048 + h * 128 + ks * 32 + quad * 8);

  float runl[4] = {0.f, 0.f, 0.f, 0.f};
  f32x4 acc_o[8] = {};

  // preload V for tile 0 (heavy path reads hidx directly -> no shx dependency)
  half8 vreg[4];
  if (ntiles > 0) {
    int jv = zz ? hidx[h * HEAVY + lane] : (tb_lo * TB + lane);
#pragma unroll
    for (int u = 0; u < 4; ++u)
      vreg[u] = *(const half8*)(vh + (size_t)jv * 512 + kvh * 128 + (u * 4 + wave) * 8);
  }
  __syncthreads();   // shx ready

  for (int tt = 0; tt < ntiles; ++tt) {
    int j0 = zz ? 0 : (tb_lo + tt) * TB;
    int e0 = zz ? tt * TB : 0;

    // stage K tile (64 cols x 128 dims): 16 lanes per row, 256B contiguous
#pragma unroll
    for (int u = 0; u < 4; ++u) {
      int unit = u * 256 + tid;
      int c = unit >> 4, d8 = (unit & 15) * 8;
      int jabs;
      if (!zz) jabs = j0 + c;
      else { int e = e0 + c; jabs = (e < HEAVY) ? shx[e] : 0; }
      *(half8*)&Ks[c][d8] = *(const half8*)(kh + (size_t)jabs * 512 + kvh * 128 + d8);
    }
    int jreg[4];
#pragma unroll
    for (int ct = 0; ct < 4; ++ct) {
      int c = ct * 16 + mq;
      if (!zz) jreg[ct] = j0 + c;
      else { int e = e0 + c; jreg[ct] = (e < HEAVY) ? shx[e] : (1 << 28); }
    }
    __syncthreads();   // bar1: Ks ready; prev-tile Vs/Ps reads complete

    // S = Q K^T
    f32x4 s[4] = {};
#pragma unroll
    for (int ks = 0; ks < 4; ++ks) {
      half8 bf[4];
#pragma unroll
      for (int ct = 0; ct < 4; ++ct) bf[ct] = *(const half8*)&Ks[ct * 16 + mq][ks * 32 + quad * 8];
#pragma unroll
      for (int ct = 0; ct < 4; ++ct)
        s[ct] = __builtin_amdgcn_mfma_f32_16x16x32_f16(aq[ks], bf[ct], s[ct], 0, 0, 0);
    }

    // mask + exp (reference 0); per-lane partial denominator; P into LDS
#pragma unroll
    for (int r = 0; r < 4; ++r) {
      int i = i0 + wm + quad * 4 + r;
      float ps = 0.f;
#pragma unroll
      for (int ct = 0; ct < 4; ++ct) {
        int j = jreg[ct];
        bool ok = zz ? (j < i - RECENT) : (j >= i - RECENT && j <= i);
        float pe = ok ? __expf(s[ct][r]) : 0.f;
        Ps[wm + quad * 4 + r][ct * 16 + mq] = (_Float16)pe;
        ps += pe;
      }
      runl[r] += ps;
    }

    // current V (prefetched) -> Vs; prefetch next tile's V
#pragma unroll
    for (int u = 0; u < 4; ++u)
#pragma unroll
      for (int e2 = 0; e2 < 8; ++e2) Vs[(u * 4 + wave) * 8 + e2][lane] = vreg[u][e2];

    if (tt + 1 < ntiles) {
      int jv;
      if (!zz) jv = (tb_lo + tt + 1) * TB + lane;
      else { int e = (tt + 1) * TB + lane; jv = (e < HEAVY) ? shx[e] : 0; }
#pragma unroll
      for (int u = 0; u < 4; ++u)
        vreg[u] = *(const half8*)(vh + (size_t)jv * 512 + kvh * 128 + (u * 4 + wave) * 8);
    }
    __syncthreads();   // bar2: Vs ready (Ps is wave-local)

    // O += P V  (no end barrier: next bar1 orders Vs reuse)
#pragma unroll
    for (int ks = 0; ks < 2; ++ks) {
      half8 ap = *(const half8*)&Ps[wm + mq][ks * 32 + quad * 8];
      half8 bf[8];
#pragma unroll
      for (int ct = 0; ct < 8; ++ct) bf[ct] = *(const half8*)&Vs[ct * 16 + mq][ks * 32 + quad * 8];
#pragma unroll
      for (int ct = 0; ct < 8; ++ct)
        acc_o[ct] = __builtin_amdgcn_mfma_f32_16x16x32_f16(ap, bf[ct], acc_o[ct], 0, 0, 0);
    }
  }

  // reduce per-lane denominators across mq, write f32 partials
#pragma unroll
  for (int r = 0; r < 4; ++r) {
    float l = runl[r];
    for (int off = 1; off < 16; off <<= 1) l += __shfl_xor(l, off, 64);
    runl[r] = l;
  }
  float* On = zz ? On1 : On0;
#pragma unroll
  for (int ct = 0; ct < 8; ++ct) {
    int d = ct * 16 + mq;
#pragma unroll
    for (int r = 0; r < 4; ++r) {
      int i = i0 + wm + quad * 4 + r;
      On[((size_t)h * SEQ + i) * 128 + d] = acc_o[ct][r];
    }
  }
  if (mq == 0) {
#pragma unroll
    for (int r = 0; r < 4; ++r) {
      int i = i0 + wm + quad * 4 + r;
      lp[zz * (NH * SEQ) + h * SEQ + i] = runl[r];
    }
  }
}

// ---------- combineO: ctx = (On0+On1) / (l0+l1), cast f16 ----------
__global__ void combineO(const float* __restrict__ On0, const float* __restrict__ On1,
                         const float* __restrict__ lp, _Float16* __restrict__ ctx) {
  int idx = blockIdx.x * 256 + threadIdx.x;   // NH*SEQ*32 threads, 4 floats each
  int row = idx >> 5;                         // h*SEQ + i
  int dq = (idx & 31) * 4;
  float l = lp[row] + lp[NH * SEQ + row];
  float inv = (l > 0.f) ? 1.f / l : 0.f;
  float4 a = *(const float4*)(On0 + (size_t)row * 128 + dq);
  float4 b = *(const float4*)(On1 + (size_t)row * 128 + dq);
  int i = row & (SEQ - 1), h = row >> 11;
  _Float16* p = ctx + (size_t)i * 2048 + h * 128 + dq;
  p[0] = (_Float16)((a.x + b.x) * inv);
  p[1] = (_Float16)((a.y + b.y) * inv);
  p[2] = (_Float16)((a.z + b.z) * inv);
  p[3] = (_Float16)((a.w + b.w) * inv);
}

// ---------- launch ----------
extern "C" void kernel_launch(void* const* d_in, const int* in_sizes, int n_in,
                              void* d_out, int out_size, void* d_ws, size_t ws_size,
                              hipStream_t stream) {
  const float* hs   = (const float*)d_in[0];
  const float* cosb = (const float*)d_in[1];
  const float* sinb = (const float*)d_in[2];
  const float* Wq = (const float*)d_in[4];
  const float* bq = (const float*)d_in[5];
  const float* Wk = (const float*)d_in[6];
  const float* bk = (const float*)d_in[7];
  const float* Wv = (const float*)d_in[8];
  const float* bv = (const float*)d_in[9];
  const float* Wo = (const float*)d_in[10];
  float* out = (float*)d_out;

  char* ws = (char*)d_ws;
  // lifetimes:  WT(12M)@0 -> [ctxH(8M)@0 + stats@9M];  qkv(24M)@12M -> [WoT(8M)@12M + On1(16M)@20M -> woP1(16M)@20M];
  //             hsH(8M)@36M -> kh+vh(4M)@36M;  qh(8M)@44M;  qkvP1(24M)@52M -> [On0(16M)@52M + lp(256K)@68M].
  _Float16* WT   = (_Float16*)ws;                       // [3072][2048] f16 12 MB @0
  _Float16* ctxH = (_Float16*)ws;                       // 8 MB @0 (after WT dead)
  float* rowlP   = (float*)(ws + (9u << 20));           // @9M: SPLIT x NH*SEQ (512 KB)
  float* rowli   = rowlP + SPLIT * NH * SEQ;            // 128 KB (1/L per row)
  float* colsumP = rowli + NH * SEQ;                    // SPLIT x NH*SEQ
  int*   hidx    = (int*)(colsumP + SPLIT * NH * SEQ);
  float* qkv     = (float*)(ws + (12u << 20));          // [2048][3072] f32 24 MB @12M
  _Float16* WoT  = (_Float16*)(ws + (12u << 20));       // 8 MB @12M (after qkv dead)
  float* On1     = (float*)(ws + (20u << 20));          // 16 MB @20M (attn3 z=1 partial)
  float* woP1    = (float*)(ws + (20u << 20));          // 16 MB @20M (AFTER combineO)
  _Float16* hsH  = (_Float16*)(ws + (36u << 20));       // 8 MB @36M
  _Float16* kh   = (_Float16*)(ws + (36u << 20));       // 2 MB @36M (after hsH dead)
  _Float16* vh   = (_Float16*)(ws + (38u << 20));       // 2 MB @38M
  _Float16* qh   = (_Float16*)(ws + (44u << 20));       // 8 MB @44M
  bool splitqkv  = ws_size >= ((size_t)76 << 20);
  float* qkvP1   = (float*)(ws + (52u << 20));          // 24 MB @52M (only if splitqkv)
  float* On0     = (float*)(ws + (52u << 20));          // 16 MB @52M (after qkvP1 dead)
  float* lp      = (float*)(ws + (68u << 20));          // 256 KB @68M

  // cvt(hs->f16) + Wq/Wk/Wv transposes in one launch
  prep<<<dim3(32, 32, 4), 256, 0, stream>>>(hs, hsH, Wq, Wk, Wv, WT);

  // fused QKV projection: split-K=2 into separate f32 partials; bias selected in epilogue
  if (splitqkv)
    gemm_h<<<dim3(3072 / 128, 2048 / 128, 2), 256, 0, stream>>>(hsH, WT, bq, bk, bv,
                                                                qkv, qkvP1, SEQ, 3072, 2048);
  else
    gemm_h<<<dim3(3072 / 128, 2048 / 128, 1), 256, 0, stream>>>(hsH, WT, bq, bk, bv,
                                                                qkv, nullptr, SEQ, 3072, 2048);

  // RoPE + f16 emit (qh pre-scaled; kh/vh); qkv and hsH dead afterwards
  int np = SEQ * 16 * 64 + SEQ * 4 * 64 + SEQ * 4 * 128;
  postproc<<<(np + 255) / 256, 256, 0, stream>>>(qkv, splitqkv ? qkvP1 : nullptr,
                                                 cosb, sinb, qh, kh, vh);

  // Wo transpose into qkv's (now dead) space
  transpose_h<<<dim3(2048 / 64, 2048 / 64), 256, 0, stream>>>(Wo, WoT, 2048, 2048);

  flashstats<<<dim3(SPLIT, SEQ / 128, NH), 256, 0, stream>>>(qh, kh, rowlP);
  mergestats<<<(NH * SEQ + 255) / 256, 256, 0, stream>>>(rowlP, rowli);
  flashcolsum<<<dim3(SPLIT, SEQ / 128, NH), 256, 0, stream>>>(qh, kh, rowli, colsumP);
  topk_radix<<<NH, 256, 0, stream>>>(colsumP, hidx);

  // sparse attention: band (z=0) / heavy (z=1) additive partials, then combine
  attn3<<<dim3(SEQ / 64, NH, 2), 256, 0, stream>>>(qh, kh, vh, hidx, On0, On1, lp);
  combineO<<<(NH * SEQ * 32) / 256, 256, 0, stream>>>(On0, On1, lp, ctxH);

  // output projection: split-K=2, partial 0 straight into out, partial 1 added after
  gemm_h<<<dim3(2048 / 128, 2048 / 128, 2), 256, 0, stream>>>(ctxH, WoT, nullptr, nullptr, nullptr,
                                                              out, woP1, SEQ, 2048, 2048);
  addout<<<(SEQ * 2048 / 4 + 255) / 256, 256, 0, stream>>>(out, woP1, SEQ * 2048);
}

// Round 14
// 315.691 us; speedup vs baseline: 1.0818x; 1.0818x over previous
//
#include <hip/hip_runtime.h>
#include <hip/hip_bf16.h>
#include <math.h>

constexpr int SEQ    = 2048;
constexpr int NH     = 16;
constexpr int HEAVY  = 204;   // int(0.1*2048)
constexpr int RECENT = 204;   // int(0.1*2048)
constexpr int SPLIT  = 4;     // flash stats/colsum split factor
constexpr float SCALE = 0.08838834764831845f; // 128^-0.5

typedef _Float16 half8 __attribute__((ext_vector_type(8)));
typedef float f32x4 __attribute__((ext_vector_type(4)));

typedef __attribute__((address_space(1))) const void cg_void;
typedef __attribute__((address_space(3))) void l_void;

// ---------- prep: z=0..2 -> transpose Wq/Wk/Wv into WT f16 [N][K]; z=3 -> hs f32->f16 ----------
__global__ __launch_bounds__(256) void prep(
    const float* __restrict__ hs, _Float16* __restrict__ hsH,
    const float* __restrict__ Wq, const float* __restrict__ Wk,
    const float* __restrict__ Wv, _Float16* __restrict__ WT) {
  int z = blockIdx.z;
  if (z < 3) {
    const float* W = (z == 0) ? Wq : ((z == 1) ? Wk : Wv);
    int N = (z == 0) ? 2048 : 512;
    size_t dstoff = (z == 0) ? 0 : ((z == 1) ? (size_t)2048 * 2048 : (size_t)2560 * 2048);
    int n0 = blockIdx.x * 64, k0 = blockIdx.y * 64;
    if (n0 >= N) return;
    __shared__ float T[64][65];
    int c = threadIdx.x & 63, rq = threadIdx.x >> 6;
#pragma unroll
    for (int u = 0; u < 16; ++u) {
      int r = rq * 16 + u;
      T[r][c] = W[(size_t)(k0 + r) * N + n0 + c];
    }
    __syncthreads();
#pragma unroll
    for (int u = 0; u < 16; ++u) {
      int r = rq * 16 + u;
      WT[dstoff + (size_t)(n0 + r) * 2048 + k0 + c] = (_Float16)T[c][r];
    }
  } else {
    int fb = blockIdx.y * 32 + blockIdx.x;
    int i = (fb * 256 + threadIdx.x) * 16;
#pragma unroll
    for (int u = 0; u < 4; ++u) {
      float4 v = *(const float4*)(hs + i + u * 4);
      hsH[i + u * 4 + 0] = (_Float16)v.x;
      hsH[i + u * 4 + 1] = (_Float16)v.y;
      hsH[i + u * 4 + 2] = (_Float16)v.z;
      hsH[i + u * 4 + 3] = (_Float16)v.w;
    }
  }
}

// ---------- transpose + convert: W f32 [K][N] -> WT f16 [N][K] (Wo) ----------
__global__ __launch_bounds__(256) void transpose_h(
    const float* __restrict__ W, _Float16* __restrict__ WT, int K, int N) {
  __shared__ float T[64][65];
  int c = threadIdx.x & 63, rq = threadIdx.x >> 6;
  int n0 = blockIdx.x * 64, k0 = blockIdx.y * 64;
#pragma unroll
  for (int u = 0; u < 16; ++u) {
    int r = rq * 16 + u;
    T[r][c] = W[(size_t)(k0 + r) * N + n0 + c];
  }
  __syncthreads();
#pragma unroll
  for (int u = 0; u < 16; ++u) {
    int r = rq * 16 + u;
    WT[(size_t)(n0 + r) * K + k0 + c] = (_Float16)T[c][r];
  }
}

// ---------- MFMA f16 GEMM, BK=64, XOR-swizzled LDS, XCD block swizzle, split-K ----------
__global__ __launch_bounds__(256) void gemm_h(
    const _Float16* __restrict__ A, const _Float16* __restrict__ BT,
    const float* __restrict__ bq, const float* __restrict__ bk,
    const float* __restrict__ bv, float* __restrict__ C0, float* __restrict__ C1,
    int M, int N, int K)
{
  __shared__ _Float16 As[128 * 64];
  __shared__ _Float16 Bs[128 * 64];
  int tid = threadIdx.x, lane = tid & 63, wave = tid >> 6;
  int wm = (wave & 1) * 64, wn = (wave >> 1) * 64;
  int mq = lane & 15, quad = lane >> 4;
  int kz = blockIdx.z, nz = gridDim.z;
  int kchunk = K / nz;
  int kbeg = kz * kchunk, kend = kbeg + kchunk;
  float* C = kz ? C1 : C0;

  int gx = gridDim.x;
  int nwg = gx * gridDim.y;
  int bid = blockIdx.y * gx + blockIdx.x;
  if ((nwg & 7) == 0) {
    int cpx = nwg >> 3;
    bid = (bid & 7) * cpx + (bid >> 3);
  }
  int m0 = (bid / gx) * 128, n0 = (bid % gx) * 128;

  f32x4 acc[4][4] = {};

  int rstage = wave * 32 + (lane >> 3);
  int qs = ((lane & 7) ^ (lane >> 3)) * 8;         // pre-swizzled k-slot (halfs)
  const _Float16* gA = A  + (size_t)(m0 + rstage) * K + qs;
  const _Float16* gB = BT + (size_t)(n0 + rstage) * K + qs;
  _Float16* lA = &As[(wave * 32) * 64];
  _Float16* lB = &Bs[(wave * 32) * 64];

  int rsw = mq & 7;                                // read-side row swizzle key

  for (int k0 = kbeg; k0 < kend; k0 += 64) {
#pragma unroll
    for (int c = 0; c < 4; ++c) {
      __builtin_amdgcn_global_load_lds((cg_void*)(gA + (size_t)(8 * c) * K + k0),
                                       (l_void*)(lA + (8 * c) * 64), 16, 0, 0);
      __builtin_amdgcn_global_load_lds((cg_void*)(gB + (size_t)(8 * c) * K + k0),
                                       (l_void*)(lB + (8 * c) * 64), 16, 0, 0);
    }
    __syncthreads();
#pragma unroll
    for (int ks2 = 0; ks2 < 2; ++ks2) {
      int sw = ((ks2 * 4 + quad) ^ rsw) * 8;
      half8 af[4], bf[4];
#pragma unroll
      for (int t4 = 0; t4 < 4; ++t4) {
        af[t4] = *(const half8*)&As[(wm + t4 * 16 + mq) * 64 + sw];
        bf[t4] = *(const half8*)&Bs[(wn + t4 * 16 + mq) * 64 + sw];
      }
#pragma unroll
      for (int mt = 0; mt < 4; ++mt)
#pragma unroll
        for (int nt = 0; nt < 4; ++nt)
          acc[mt][nt] = __builtin_amdgcn_mfma_f32_16x16x32_f16(af[mt], bf[nt], acc[mt][nt], 0, 0, 0);
    }
    __syncthreads();
  }

#pragma unroll
  for (int mt = 0; mt < 4; ++mt)
#pragma unroll
    for (int nt = 0; nt < 4; ++nt) {
      int n = n0 + wn + nt * 16 + mq;
      float bb = 0.f;
      if (bq && kz == 0)
        bb = (n < 2048) ? bq[n] : ((n < 2560) ? bk[n - 2048] : bv[n - 2560]);
#pragma unroll
      for (int r = 0; r < 4; ++r) {
        int m = m0 + wm + mt * 16 + quad * 4 + r;
        C[(size_t)m * N + n] = acc[mt][nt][r] + bb;
      }
    }
}

// ---------- add partial into out ----------
__global__ void addout(float* __restrict__ out, const float* __restrict__ p1, int n) {
  int i = (blockIdx.x * 256 + threadIdx.x) * 4;
  if (i + 3 < n) {
    float4 a = *(const float4*)(out + i);
    float4 b = *(const float4*)(p1 + i);
    a.x += b.x; a.y += b.y; a.z += b.z; a.w += b.w;
    *(float4*)(out + i) = a;
  } else {
    for (int u = i; u < n; ++u) out[u] += p1[u];
  }
}

// ---------- postproc: qkv partials -> RoPE'd qh (PRE-SCALED by SCALE) / kh + vh ----------
__global__ void postproc(const float* __restrict__ qkv, const float* __restrict__ qkv1,
                         const float* __restrict__ cosb, const float* __restrict__ sinb,
                         _Float16* __restrict__ qh, _Float16* __restrict__ kh,
                         _Float16* __restrict__ vh) {
  int idx = blockIdx.x * 256 + threadIdx.x;
  const int NQ = SEQ * 16 * 64, NK = SEQ * 4 * 64, NV = SEQ * 4 * 128;
  bool sp = (qkv1 != nullptr);
  if (idx < NQ) {
    int d = idx & 63; int rest = idx >> 6; int h = rest & 15; int s = rest >> 4;
    size_t o = (size_t)s * 3072 + h * 128;
    float x1 = qkv[o + d]      + (sp ? qkv1[o + d] : 0.f);
    float x2 = qkv[o + d + 64] + (sp ? qkv1[o + d + 64] : 0.f);
    float c1 = cosb[(size_t)s * 128 + d], c2 = cosb[(size_t)s * 128 + d + 64];
    float s1 = sinb[(size_t)s * 128 + d], s2 = sinb[(size_t)s * 128 + d + 64];
    qh[(size_t)s * 2048 + h * 128 + d]      = (_Float16)((x1 * c1 - x2 * s1) * SCALE);
    qh[(size_t)s * 2048 + h * 128 + d + 64] = (_Float16)((x2 * c2 + x1 * s2) * SCALE);
  } else if (idx < NQ + NK) {
    int r = idx - NQ;
    int d = r & 63; int rest = r >> 6; int h = rest & 3; int s = rest >> 2;
    size_t o = (size_t)s * 3072 + 2048 + h * 128;
    float x1 = qkv[o + d]      + (sp ? qkv1[o + d] : 0.f);
    float x2 = qkv[o + d + 64] + (sp ? qkv1[o + d + 64] : 0.f);
    float c1 = cosb[(size_t)s * 128 + d], c2 = cosb[(size_t)s * 128 + d + 64];
    float s1 = sinb[(size_t)s * 128 + d], s2 = sinb[(size_t)s * 128 + d + 64];
    kh[(size_t)s * 512 + h * 128 + d]      = (_Float16)(x1 * c1 - x2 * s1);
    kh[(size_t)s * 512 + h * 128 + d + 64] = (_Float16)(x2 * c2 + x1 * s2);
  } else if (idx < NQ + NK + NV) {
    int r = idx - NQ - NK;
    int d = r & 127; int rest = r >> 7; int h = rest & 3; int s = rest >> 2;
    size_t o = (size_t)s * 3072 + 2560 + h * 128 + d;
    float x = qkv[o] + (sp ? qkv1[o] : 0.f);
    vh[(size_t)s * 512 + h * 128 + d] = (_Float16)x;
  }
}

// ---------- S1: denominator L_i = sum_{j<=i} exp(s_ij), reference point 0 ----------
__global__ __launch_bounds__(256) void flashstats(
    const _Float16* __restrict__ qh, const _Float16* __restrict__ kh,
    float* __restrict__ rowlP)
{
  int sp = blockIdx.x;                    // j-split 0..SPLIT-1
  int ib = blockIdx.y;
  int i0 = ib * 128, h = blockIdx.z, kvh = h >> 2;
  __shared__ _Float16 Ks[128][136];
  int tid = threadIdx.x, lane = tid & 63, wave = tid >> 6;
  int mq = lane & 15, quad = lane >> 4;
  int wm = wave * 32;

  half8 aq[2][4];
#pragma unroll
  for (int rt = 0; rt < 2; ++rt)
#pragma unroll
    for (int ks = 0; ks < 4; ++ks)
      aq[rt][ks] = *(const half8*)(qh + (size_t)(i0 + wm + rt * 16 + mq) * 2048 + h * 128 + ks * 32 + quad * 8);

  float runl[2][4] = {};

  int nblk = ib + 1;
  int jb_lo = (sp * nblk) / SPLIT;
  int jb_hi = ((sp + 1) * nblk) / SPLIT;
  for (int jb = jb_lo; jb < jb_hi; ++jb) {
    int j0 = jb * 128;
    __syncthreads();
#pragma unroll
    for (int u = 0; u < 8; ++u) {
      int unit = u * 256 + tid;
      int r = unit >> 4, c8 = (unit & 15) * 8;
      *(half8*)&Ks[r][c8] = *(const half8*)(kh + (size_t)(j0 + r) * 512 + kvh * 128 + c8);
    }
    __syncthreads();

    f32x4 acc[2][8] = {};
#pragma unroll
    for (int ks = 0; ks < 4; ++ks) {
      half8 bf[8];
#pragma unroll
      for (int ct = 0; ct < 8; ++ct) bf[ct] = *(const half8*)&Ks[ct * 16 + mq][ks * 32 + quad * 8];
#pragma unroll
      for (int rt = 0; rt < 2; ++rt)
#pragma unroll
        for (int ct = 0; ct < 8; ++ct)
          acc[rt][ct] = __builtin_amdgcn_mfma_f32_16x16x32_f16(aq[rt][ks], bf[ct], acc[rt][ct], 0, 0, 0);
    }

    if (jb < ib) {
#pragma unroll
      for (int rt = 0; rt < 2; ++rt)
#pragma unroll
        for (int r = 0; r < 4; ++r) {
          float ps = 0.f;
#pragma unroll
          for (int ct = 0; ct < 8; ++ct) ps += __expf(acc[rt][ct][r]);
          runl[rt][r] += ps;
        }
    } else {
#pragma unroll
      for (int rt = 0; rt < 2; ++rt) {
        int rbase = i0 + wm + rt * 16 + quad * 4;
#pragma unroll
        for (int r = 0; r < 4; ++r) {
          float ps = 0.f;
#pragma unroll
          for (int ct = 0; ct < 8; ++ct) {
            int j = j0 + ct * 16 + mq;
            ps += (j <= rbase + r) ? __expf(acc[rt][ct][r]) : 0.f;
          }
          runl[rt][r] += ps;
        }
      }
    }
  }

#pragma unroll
  for (int rt = 0; rt < 2; ++rt)
#pragma unroll
    for (int r = 0; r < 4; ++r) {
      float l = runl[rt][r];
      for (int off = 1; off < 16; off <<= 1) l += __shfl_xor(l, off, 64);
      runl[rt][r] = l;
    }

  if (mq == 0) {
#pragma unroll
    for (int rt = 0; rt < 2; ++rt)
#pragma unroll
      for (int r = 0; r < 4; ++r) {
        int i = i0 + wm + rt * 16 + quad * 4 + r;
        rowlP[sp * (NH * SEQ) + h * SEQ + i] = runl[rt][r];
      }
  }
}

// ---------- merge: rowli[i] = 1 / sum_s rowlP[s][i] ----------
__global__ void mergestats(const float* __restrict__ rowlP, float* __restrict__ rowli) {
  int i = blockIdx.x * 256 + threadIdx.x;
  if (i >= NH * SEQ) return;
  float l = 0.f;
#pragma unroll
  for (int s = 0; s < SPLIT; ++s) l += rowlP[s * (NH * SEQ) + i];
  rowli[i] = (l > 0.f) ? 1.f / l : 0.f;
}

// ---------- S2: colsum[h][j] = sum_i exp(s_ij) * rowli[i], Q streamed, i-split ----------
__global__ __launch_bounds__(256) void flashcolsum(
    const _Float16* __restrict__ qh, const _Float16* __restrict__ kh,
    const float* __restrict__ rowli, float* __restrict__ colsumP)
{
  int sp = blockIdx.x;                    // i-split 0..SPLIT-1
  int jb = blockIdx.y;
  int j0 = jb * 128, h = blockIdx.z, kvh = h >> 2;
  __shared__ _Float16 Ks[128][136];
  __shared__ float colred[4][128];
  int tid = threadIdx.x, lane = tid & 63, wave = tid >> 6;
  int mq = lane & 15, quad = lane >> 4;
  int wm = wave * 32;

#pragma unroll
  for (int u = 0; u < 8; ++u) {
    int unit = u * 256 + tid;
    int r = unit >> 4, c8 = (unit & 15) * 8;
    *(half8*)&Ks[r][c8] = *(const half8*)(kh + (size_t)(j0 + r) * 512 + kvh * 128 + c8);
  }
  __syncthreads();

  float colacc[8] = {};
  int n = SEQ / 128 - jb;
  int ib_lo = jb + (sp * n) / SPLIT;
  int ib_hi = jb + ((sp + 1) * n) / SPLIT;
  for (int ib = ib_lo; ib < ib_hi; ++ib) {
    int i0 = ib * 128;

    f32x4 acc[2][8] = {};
#pragma unroll
    for (int ks = 0; ks < 4; ++ks) {
      half8 af[2], bf[8];
#pragma unroll
      for (int rt = 0; rt < 2; ++rt)
        af[rt] = *(const half8*)(qh + (size_t)(i0 + wm + rt * 16 + mq) * 2048 + h * 128 + ks * 32 + quad * 8);
#pragma unroll
      for (int ct = 0; ct < 8; ++ct) bf[ct] = *(const half8*)&Ks[ct * 16 + mq][ks * 32 + quad * 8];
#pragma unroll
      for (int rt = 0; rt < 2; ++rt)
#pragma unroll
        for (int ct = 0; ct < 8; ++ct)
          acc[rt][ct] = __builtin_amdgcn_mfma_f32_16x16x32_f16(af[rt], bf[ct], acc[rt][ct], 0, 0, 0);
    }

    if (ib > jb) {
#pragma unroll
      for (int rt = 0; rt < 2; ++rt) {
        int rbase = i0 + wm + rt * 16 + quad * 4;
        float ri[4];
#pragma unroll
        for (int r = 0; r < 4; ++r) ri[r] = rowli[h * SEQ + rbase + r];
#pragma unroll
        for (int ct = 0; ct < 8; ++ct) {
          float cp = 0.f;
#pragma unroll
          for (int r = 0; r < 4; ++r) cp += __expf(acc[rt][ct][r]) * ri[r];
          colacc[ct] += cp;
        }
      }
    } else {
#pragma unroll
      for (int rt = 0; rt < 2; ++rt) {
        int rbase = i0 + wm + rt * 16 + quad * 4;
        float ri[4];
#pragma unroll
        for (int r = 0; r < 4; ++r) ri[r] = rowli[h * SEQ + rbase + r];
#pragma unroll
        for (int ct = 0; ct < 8; ++ct) {
          int j = j0 + ct * 16 + mq;
          float cp = 0.f;
#pragma unroll
          for (int r = 0; r < 4; ++r) {
            if (j <= rbase + r) cp += __expf(acc[rt][ct][r]) * ri[r];
          }
          colacc[ct] += cp;
        }
      }
    }
  }
#pragma unroll
  for (int ct = 0; ct < 8; ++ct) {
    float v = colacc[ct];
    v += __shfl_xor(v, 16, 64);
    v += __shfl_xor(v, 32, 64);
    colacc[ct] = v;
  }
  __syncthreads();
  if (quad == 0) {
#pragma unroll
    for (int ct = 0; ct < 8; ++ct) colred[wave][ct * 16 + mq] = colacc[ct];
  }
  __syncthreads();
  if (tid < 128)
    colsumP[sp * (NH * SEQ) + h * SEQ + j0 + tid] =
        colred[0][tid] + colred[1][tid] + colred[2][tid] + colred[3][tid];
}

// ---------- top-HEAVY per head via radix select, parallel suffix-scan bucket pick ----------
__global__ __launch_bounds__(256) void topk_radix(const float* __restrict__ colsumP,
                                                  int* __restrict__ hidx) {
  int h = blockIdx.x, t = threadIdx.x;
  __shared__ unsigned vals[SEQ];
  __shared__ int hist[256];
  __shared__ int scanbuf[256];
  __shared__ unsigned s_prefix;
  __shared__ int s_k;

  for (int j = t; j < SEQ; j += 256) {
    float cs = 0.f;
#pragma unroll
    for (int s = 0; s < SPLIT; ++s) cs += colsumP[s * (NH * SEQ) + h * SEQ + j];
    vals[j] = __float_as_uint(cs);
  }

  unsigned prefix = 0, maskFixed = 0;
  int k = HEAVY;
  for (int pass = 0; pass < 4; ++pass) {
    int shift = 24 - pass * 8;
    hist[t] = 0;
    __syncthreads();
    for (int j = t; j < SEQ; j += 256) {
      unsigned v = vals[j];
      if ((v & maskFixed) == prefix) atomicAdd(&hist[(v >> shift) & 255], 1);
    }
    __syncthreads();
    scanbuf[t] = hist[t];
    __syncthreads();
    for (int off = 1; off < 256; off <<= 1) {
      int x = (t + off < 256) ? scanbuf[t + off] : 0;
      __syncthreads();
      scanbuf[t] += x;
      __syncthreads();
    }
    int S = scanbuf[t];
    int Snext = (t < 255) ? scanbuf[t + 1] : 0;
    if (S >= k && Snext < k) {
      s_prefix = prefix | ((unsigned)t << shift);
      s_k = k - (S - hist[t]);
    }
    __syncthreads();
    prefix = s_prefix;
    k = s_k;
    maskFixed |= (0xFFu << shift);
    __syncthreads();
  }
  unsigned T = prefix;
  int tieNeed = k;

  int base = t * 8;
  int cG = 0, cT = 0;
#pragma unroll
  for (int u = 0; u < 8; ++u) {
    unsigned v = vals[base + u];
    if (v > T) cG++;
    else if (v == T) cT++;
  }
  scanbuf[t] = cG; __syncthreads();
  for (int off = 1; off < 256; off <<= 1) {
    int x = (t >= off) ? scanbuf[t - off] : 0;
    __syncthreads();
    scanbuf[t] += x;
    __syncthreads();
  }
  int exG = scanbuf[t] - cG;
  int totG = scanbuf[255];
  __syncthreads();
  scanbuf[t] = cT; __syncthreads();
  for (int off = 1; off < 256; off <<= 1) {
    int x = (t >= off) ? scanbuf[t - off] : 0;
    __syncthreads();
    scanbuf[t] += x;
    __syncthreads();
  }
  int exT = scanbuf[t] - cT;

  int slotG = exG;
  int slotT = totG + exT;
#pragma unroll
  for (int u = 0; u < 8; ++u) {
    unsigned v = vals[base + u];
    if (v > T) {
      hidx[h * HEAVY + slotG] = base + u;
      slotG++;
    } else if (v == T) {
      if (slotT < totG + tieNeed) hidx[h * HEAVY + slotT] = base + u;
      slotT++;
    }
  }
}

// ---------- attn3: sparse flash attention, reference point 0, K staged via LDS ----------
// R12 structure + redundant end-of-loop barrier removed (PV reads only Vs/Ps;
// waves reach next-tile bar1 only after finishing PV, so Vs rewrite after bar1
// is ordered; Ks restage touches a buffer PV never reads).  2 barriers/tile.
// V prefetched one tile ahead.
__global__ __launch_bounds__(256) void attn3(
    const _Float16* __restrict__ qh, const _Float16* __restrict__ kh,
    const _Float16* __restrict__ vh, const int* __restrict__ hidx,
    _Float16* __restrict__ ctx)
{
  constexpr int TB = 64;
  int i0 = blockIdx.x * 64, h = blockIdx.y, kvh = h >> 2;
  __shared__ _Float16 Ks[64][136];        // K tile
  __shared__ _Float16 Vs[128][72];        // V^T tile
  __shared__ _Float16 Ps[64][72];         // P tile (wave-local rows)
  __shared__ int shx[HEAVY];
  int tid = threadIdx.x, lane = tid & 63, wave = tid >> 6;
  int mq = lane & 15, quad = lane >> 4;
  int wm = wave * 16;

  for (int e = tid; e < HEAVY; e += 256) shx[e] = hidx[h * HEAVY + e];

  half8 aq[4];
#pragma unroll
  for (int ks = 0; ks < 4; ++ks)
    aq[ks] = *(const half8*)(qh + (size_t)(i0 + wm + mq) * 2048 + h * 128 + ks * 32 + quad * 8);

  float runl[4] = {0.f, 0.f, 0.f, 0.f};
  f32x4 acc_o[8] = {};

  int tb_lo = max(0, i0 - RECENT) >> 6;
  int tb_hi = (i0 + 63) >> 6;
  int nband = tb_hi - tb_lo + 1;
  int nheavy = (i0 + 63 > RECENT) ? ((HEAVY + TB - 1) / TB) : 0;
  int ntiles = nband + nheavy;

  // preload V for tile 0 (always a band tile -> no shx dependency)
  half8 vreg[4];
  {
    int jv = tb_lo * TB + lane;
#pragma unroll
    for (int u = 0; u < 4; ++u)
      vreg[u] = *(const half8*)(vh + (size_t)jv * 512 + kvh * 128 + (u * 4 + wave) * 8);
  }
  __syncthreads();   // shx ready

  for (int tt = 0; tt < ntiles; ++tt) {
    bool isheavy = tt >= nband;
    int j0 = isheavy ? 0 : (tb_lo + tt) * TB;
    int e0 = isheavy ? (tt - nband) * TB : 0;

    // stage K tile (64 cols x 128 dims): 16 lanes per row, 256B contiguous
#pragma unroll
    for (int u = 0; u < 4; ++u) {
      int unit = u * 256 + tid;
      int c = unit >> 4, d8 = (unit & 15) * 8;
      int jabs;
      if (!isheavy) jabs = j0 + c;
      else { int e = e0 + c; jabs = (e < HEAVY) ? shx[e] : 0; }
      *(half8*)&Ks[c][d8] = *(const half8*)(kh + (size_t)jabs * 512 + kvh * 128 + d8);
    }
    int jreg[4];
#pragma unroll
    for (int ct = 0; ct < 4; ++ct) {
      int c = ct * 16 + mq;
      if (!isheavy) jreg[ct] = j0 + c;
      else { int e = e0 + c; jreg[ct] = (e < HEAVY) ? shx[e] : (1 << 28); }
    }
    __syncthreads();   // bar1: Ks ready; prev-tile Vs/Ps reads complete

    // S = Q K^T
    f32x4 s[4] = {};
#pragma unroll
    for (int ks = 0; ks < 4; ++ks) {
      half8 bf[4];
#pragma unroll
      for (int ct = 0; ct < 4; ++ct) bf[ct] = *(const half8*)&Ks[ct * 16 + mq][ks * 32 + quad * 8];
#pragma unroll
      for (int ct = 0; ct < 4; ++ct)
        s[ct] = __builtin_amdgcn_mfma_f32_16x16x32_f16(aq[ks], bf[ct], s[ct], 0, 0, 0);
    }

    // mask + exp (reference 0); per-lane partial denominator; P into LDS
#pragma unroll
    for (int r = 0; r < 4; ++r) {
      int i = i0 + wm + quad * 4 + r;
      float ps = 0.f;
#pragma unroll
      for (int ct = 0; ct < 4; ++ct) {
        int j = jreg[ct];
        bool ok = isheavy ? (j < i - RECENT) : (j >= i - RECENT && j <= i);
        float pe = ok ? __expf(s[ct][r]) : 0.f;
        Ps[wm + quad * 4 + r][ct * 16 + mq] = (_Float16)pe;
        ps += pe;
      }
      runl[r] += ps;
    }

    // write current V tile (prefetched) into Vs; then prefetch NEXT tile's V
#pragma unroll
    for (int u = 0; u < 4; ++u)
#pragma unroll
      for (int e2 = 0; e2 < 8; ++e2) Vs[(u * 4 + wave) * 8 + e2][lane] = vreg[u][e2];

    if (tt + 1 < ntiles) {
      bool nh2 = (tt + 1) >= nband;
      int jv;
      if (!nh2) jv = (tb_lo + tt + 1) * TB + lane;
      else { int e = (tt + 1 - nband) * TB + lane; jv = (e < HEAVY) ? shx[e] : 0; }
#pragma unroll
      for (int u = 0; u < 4; ++u)
        vreg[u] = *(const half8*)(vh + (size_t)jv * 512 + kvh * 128 + (u * 4 + wave) * 8);
    }
    __syncthreads();   // bar2: Vs ready (Ps is wave-local)

    // O += P V   (no end barrier: next bar1 orders Vs/Ks reuse)
#pragma unroll
    for (int ks = 0; ks < 2; ++ks) {
      half8 ap = *(const half8*)&Ps[wm + mq][ks * 32 + quad * 8];
      half8 bf[8];
#pragma unroll
      for (int ct = 0; ct < 8; ++ct) bf[ct] = *(const half8*)&Vs[ct * 16 + mq][ks * 32 + quad * 8];
#pragma unroll
      for (int ct = 0; ct < 8; ++ct)
        acc_o[ct] = __builtin_amdgcn_mfma_f32_16x16x32_f16(ap, bf[ct], acc_o[ct], 0, 0, 0);
    }
  }

#pragma unroll
  for (int r = 0; r < 4; ++r) {
    float l = runl[r];
    for (int off = 1; off < 16; off <<= 1) l += __shfl_xor(l, off, 64);
    runl[r] = l;
  }
  float inv[4];
#pragma unroll
  for (int r = 0; r < 4; ++r) inv[r] = (runl[r] > 0.f) ? 1.f / runl[r] : 0.f;
#pragma unroll
  for (int ct = 0; ct < 8; ++ct) {
    int d = ct * 16 + mq;
#pragma unroll
    for (int r = 0; r < 4; ++r) {
      int i = i0 + wm + quad * 4 + r;
      ctx[(size_t)i * 2048 + h * 128 + d] = (_Float16)(acc_o[ct][r] * inv[r]);
    }
  }
}

// ---------- launch ----------
extern "C" void kernel_launch(void* const* d_in, const int* in_sizes, int n_in,
                              void* d_out, int out_size, void* d_ws, size_t ws_size,
                              hipStream_t stream) {
  const float* hs   = (const float*)d_in[0];
  const float* cosb = (const float*)d_in[1];
  const float* sinb = (const float*)d_in[2];
  const float* Wq = (const float*)d_in[4];
  const float* bq = (const float*)d_in[5];
  const float* Wk = (const float*)d_in[6];
  const float* bk = (const float*)d_in[7];
  const float* Wv = (const float*)d_in[8];
  const float* bv = (const float*)d_in[9];
  const float* Wo = (const float*)d_in[10];
  float* out = (float*)d_out;

  char* ws = (char*)d_ws;
  _Float16* WT   = (_Float16*)ws;                       // [3072][2048] f16 12 MB @0
  _Float16* ctxH = (_Float16*)ws;                       // 8 MB @0 (after WT dead)
  float* rowlP   = (float*)(ws + (9u << 20));           // @9M: SPLIT x NH*SEQ (512 KB)
  float* rowli   = rowlP + SPLIT * NH * SEQ;            // 128 KB (1/L per row)
  float* colsumP = rowli + NH * SEQ;                    // SPLIT x NH*SEQ
  int*   hidx    = (int*)(colsumP + SPLIT * NH * SEQ);
  float* qkv     = (float*)(ws + (12u << 20));          // [2048][3072] f32 24 MB @12M
  _Float16* WoT  = (_Float16*)(ws + (12u << 20));       // 8 MB @12M (after qkv dead)
  float* woP1    = (float*)(ws + (20u << 20));          // 16 MB @20M (after qkv dead)
  _Float16* hsH  = (_Float16*)(ws + (36u << 20));       // 8 MB @36M
  _Float16* kh   = (_Float16*)(ws + (36u << 20));       // 2 MB @36M (after hsH dead)
  _Float16* vh   = (_Float16*)(ws + (38u << 20));       // 2 MB @38M
  _Float16* qh   = (_Float16*)(ws + (44u << 20));       // 8 MB @44M
  bool splitqkv  = ws_size >= ((size_t)76 << 20);
  float* qkvP1   = (float*)(ws + (52u << 20));          // 24 MB @52M (only if splitqkv)

  // cvt(hs->f16) + Wq/Wk/Wv transposes in one launch
  prep<<<dim3(32, 32, 4), 256, 0, stream>>>(hs, hsH, Wq, Wk, Wv, WT);

  // fused QKV projection: split-K=2 into separate f32 partials; bias selected in epilogue
  if (splitqkv)
    gemm_h<<<dim3(3072 / 128, 2048 / 128, 2), 256, 0, stream>>>(hsH, WT, bq, bk, bv,
                                                                qkv, qkvP1, SEQ, 3072, 2048);
  else
    gemm_h<<<dim3(3072 / 128, 2048 / 128, 1), 256, 0, stream>>>(hsH, WT, bq, bk, bv,
                                                                qkv, nullptr, SEQ, 3072, 2048);

  // RoPE + f16 emit (qh pre-scaled; kh/vh); qkv and hsH dead afterwards
  int np = SEQ * 16 * 64 + SEQ * 4 * 64 + SEQ * 4 * 128;
  postproc<<<(np + 255) / 256, 256, 0, stream>>>(qkv, splitqkv ? qkvP1 : nullptr,
                                                 cosb, sinb, qh, kh, vh);

  // Wo transpose into qkv's (now dead) space
  transpose_h<<<dim3(2048 / 64, 2048 / 64), 256, 0, stream>>>(Wo, WoT, 2048, 2048);

  flashstats<<<dim3(SPLIT, SEQ / 128, NH), 256, 0, stream>>>(qh, kh, rowlP);
  mergestats<<<(NH * SEQ + 255) / 256, 256, 0, stream>>>(rowlP, rowli);
  flashcolsum<<<dim3(SPLIT, SEQ / 128, NH), 256, 0, stream>>>(qh, kh, rowli, colsumP);
  topk_radix<<<NH, 256, 0, stream>>>(colsumP, hidx);
  attn3<<<dim3(SEQ / 64, NH), 256, 0, stream>>>(qh, kh, vh, hidx, ctxH);

  // output projection: split-K=2, partial 0 straight into out, partial 1 added after
  gemm_h<<<dim3(2048 / 128, 2048 / 128, 2), 256, 0, stream>>>(ctxH, WoT, nullptr, nullptr, nullptr,
                                                              out, woP1, SEQ, 2048, 2048);
  addout<<<(SEQ * 2048 / 4 + 255) / 256, 256, 0, stream>>>(out, woP1, SEQ * 2048);
}